// Round 8
// baseline (988.079 us; speedup 1.0000x reference)
//
#include <hip/hip_runtime.h>
#include <hip/hip_bf16.h>
#include <stdint.h>

#define EPS_BN 1e-5f
constexpr int PP = 16384;   // 128*128 pixels at fusion resolution
using short8 = __attribute__((ext_vector_type(8))) short;
using f32x4  = __attribute__((ext_vector_type(4))) float;
typedef unsigned short u16;

__device__ inline float bf2f(u16 u) {
  unsigned v = ((unsigned)u) << 16; float f; __builtin_memcpy(&f, &v, 4); return f;
}
__device__ inline u16 f2bf(float f) {
  unsigned b; __builtin_memcpy(&b, &f, 4);
  b += 0x7FFFu + ((b >> 16) & 1u);
  return (u16)(b >> 16);
}

#define GLD16(g, l) __builtin_amdgcn_global_load_lds( \
    (__attribute__((address_space(1))) void*)(void*)(g), \
    (__attribute__((address_space(3))) void*)(void*)(l), 16, 0, 0)

// ---------------- BN param prep ----------------
__global__ void bn_prep_k(const float* __restrict__ g0, const float* __restrict__ b0,
                          const float* __restrict__ m0, const float* __restrict__ v0,
                          const float* __restrict__ cg, const float* __restrict__ cb,
                          const float* __restrict__ cm, const float* __restrict__ cv,
                          const float* __restrict__ eg, const float* __restrict__ eb,
                          const float* __restrict__ em, const float* __restrict__ ev,
                          float* __restrict__ scale, float* __restrict__ shift) {
  int c = threadIdx.x;
  float s = g0[c] * rsqrtf(v0[c] + EPS_BN);
  scale[c] = s; shift[c] = b0[c] - m0[c] * s;
#pragma unroll
  for (int i = 0; i < 4; ++i) {
    float si = cg[i*256+c] * rsqrtf(cv[i*256+c] + EPS_BN);
    scale[(1+i)*256+c] = si; shift[(1+i)*256+c] = cb[i*256+c] - cm[i*256+c]*si;
  }
  float se = eg[c] * rsqrtf(ev[c] + EPS_BN);
  scale[5*256+c] = se; shift[5*256+c] = eb[c] - em[c]*se;
}

// ---------------- weight prep: w[O][256][KK] fp32 -> W2[o][k*256+c] bf16, pad o>=Ocnt
__global__ void prep_w_k(const float* __restrict__ w, u16* __restrict__ W2,
                         int Ocnt, int KK, int NPAD) {
  int idx = blockIdx.x * 256 + threadIdx.x;
  int total = NPAD * KK * 256;
  if (idx >= total) return;
  int o = idx / (KK * 256); int rem = idx - o * (KK * 256);
  int kpt = rem >> 8, c = rem & 255;
  W2[idx] = (o < Ocnt) ? f2bf(w[(o * 256 + c) * KK + kpt]) : (u16)0;
}

// ---------------- NCHW fp32 -> NHWC bf16 transpose
__global__ void tr_k(const float* __restrict__ in, u16* __restrict__ out, int P) {
  __shared__ float tile[64][65];
  int p0 = blockIdx.x * 64, c0 = blockIdx.y * 64;
  int t = threadIdx.x;
  int tl = t & 63, tg = t >> 6;
#pragma unroll
  for (int i = 0; i < 16; ++i) {
    int c = tg * 16 + i;
    tile[c][tl] = in[(size_t)(c0 + c) * P + p0 + tl];
  }
  __syncthreads();
  int px = t >> 2, cq = t & 3;
#pragma unroll
  for (int pass = 0; pass < 2; ++pass) {
    int c = cq * 8 + pass * 32;
    u16 r[8];
#pragma unroll
    for (int j = 0; j < 8; ++j) r[j] = f2bf(tile[c + j][px]);
    *(short8*)(out + (size_t)(p0 + px) * 256 + c0 + c) = *(short8*)r;
  }
}

// ---------------- bilinear resize (align_corners) NHWC bf16 -> 128x128 NHWC bf16
__global__ void rs_k(const u16* __restrict__ in, u16* __restrict__ out, int Hs) {
  int t = threadIdx.x;
  int p = blockIdx.x * 8 + (t >> 5), q = t & 31;
  int oy = p >> 7, ox = p & 127;
  float sc = (float)(Hs - 1) / 127.0f;
  float ys = oy * sc, xs = ox * sc;
  int y0 = (int)ys; if (y0 > Hs - 2) y0 = Hs - 2;
  int x0 = (int)xs; if (x0 > Hs - 2) x0 = Hs - 2;
  float wy = ys - (float)y0, wx = xs - (float)x0;
  const u16* b00 = in + ((size_t)(y0 * Hs + x0)) * 256 + q * 8;
  short8 v00 = *(const short8*)b00;
  short8 v01 = *(const short8*)(b00 + 256);
  short8 v10 = *(const short8*)(b00 + (size_t)Hs * 256);
  short8 v11 = *(const short8*)(b00 + (size_t)Hs * 256 + 256);
  u16 r[8];
#pragma unroll
  for (int j = 0; j < 8; ++j) {
    float a = bf2f((u16)v00[j]) * (1.f - wx) + bf2f((u16)v01[j]) * wx;
    float b = bf2f((u16)v10[j]) * (1.f - wx) + bf2f((u16)v11[j]) * wx;
    r[j] = f2bf(a * (1.f - wy) + b * wy);
  }
  *(short8*)(out + (size_t)p * 256 + q * 8) = *(short8*)r;
}

// ---------------- deform-conv MFMA GEMM: A sampled into registers, B triple-buf LDS
// C[p,oc] = sum_k sample(A)[p,k] * Bw[oc,k];  Bw [256][2304] bf16
// Block: 256 thr (4 waves), BM=128 (wave w -> rows w*32..w*32+31, 2 A-frags), BN=256, BK=32.
// One raw s_barrier per K-step; B stage for ks+1 stays in flight across it (counted vmcnt
// from interp's gather-wait). Triple buffer => writer is always 2 bufs from any reader.
// EPI 2: plain bf16 out [p][256]   EPI 3: bn+relu bf16 out
template<int EPI>
__launch_bounds__(256, 2)
__global__ void dc_k(const u16* __restrict__ A, const u16* __restrict__ Bw,
                     const float* __restrict__ offs, u16* __restrict__ oB,
                     const float* __restrict__ scale, const float* __restrict__ shift) {
  __shared__ u16 sB[3][256 * 32];
  const int t = threadIdx.x, w = t >> 6, l = t & 63, lr = l & 15, lq = l >> 4;
  int bx = blockIdx.x; { int n8 = gridDim.x >> 3; bx = (bx & 7) * n8 + (bx >> 3); }
  const int p0 = bx * 128;
  const int gp0 = p0 + w * 32 + lr;    // pixel of A-frag 0; frag 1 = +16

  f32x4 acc[2][16];
#pragma unroll
  for (int r = 0; r < 2; ++r)
#pragma unroll
    for (int n = 0; n < 16; ++n) acc[r][n] = (f32x4){0.f, 0.f, 0.f, 0.f};

  float wgt[2][4];
  int   cb[2][4];
  short8 cv[2][4];
  float2 onext[2];
  const short8 z8 = (short8){0, 0, 0, 0, 0, 0, 0, 0};

  // B-stage offsets (pre-swizzled), constant per thread
  unsigned boff[4];
#pragma unroll
  for (int it = 0; it < 4; ++it) {
    int ch = it * 256 + t, row = ch >> 2, s = ch & 3;
    int cl = s ^ ((row ^ (row >> 2)) & 3);
    boff[it] = (unsigned)(row * 2304 + cl * 8);
  }

  onext[0] = *(const float2*)(offs + (size_t)gp0 * 32);
  onext[1] = *(const float2*)(offs + (size_t)(gp0 + 16) * 32);

  auto newKpt = [&](int kpt) {
    float ky = (float)(kpt / 3 - 1), kx = (float)(kpt % 3 - 1);
#pragma unroll
    for (int r = 0; r < 2; ++r) {
      int g = gp0 + r * 16;
      float2 o2 = onext[r];
      if (kpt < 8) onext[r] = *(const float2*)(offs + (size_t)g * 32 + 2 * (kpt + 1));
      int pl = g & 16383, lb = g & ~16383;
      float yy = (float)(pl >> 7) + ky + o2.x;
      float xx = (float)(pl & 127) + kx + o2.y;
      float yf = floorf(yy), xf = floorf(xx);
      float fy = yy - yf, fx = xx - xf;
      int y0 = (int)yf, x0 = (int)xf;
      bool va = (unsigned)y0 < 128u, vb = (unsigned)(y0 + 1) < 128u;
      bool ha = (unsigned)x0 < 128u, hb = (unsigned)(x0 + 1) < 128u;
      wgt[r][0] = (1.f - fy) * (1.f - fx); cb[r][0] = (va && ha) ? lb + (y0 << 7) + x0 : -1;
      wgt[r][1] = (1.f - fy) * fx;         cb[r][1] = (va && hb) ? lb + (y0 << 7) + x0 + 1 : -1;
      wgt[r][2] = fy * (1.f - fx);         cb[r][2] = (vb && ha) ? lb + ((y0 + 1) << 7) + x0 : -1;
      wgt[r][3] = fy * fx;                 cb[r][3] = (vb && hb) ? lb + ((y0 + 1) << 7) + x0 + 1 : -1;
    }
  };
  auto loadC = [&](int ks) {
    int cc = ((ks & 7) << 5) + lq * 8;
#pragma unroll
    for (int r = 0; r < 2; ++r)
#pragma unroll
      for (int c = 0; c < 4; ++c)
        cv[r][c] = (cb[r][c] >= 0) ? *(const short8*)(A + (size_t)cb[r][c] * 256 + cc) : z8;
  };
  auto stageB = [&](int ks) {
    const u16* bbase = Bw + ks * 32;
    char* dst = (char*)sB[ks % 3] + w * 1024;
#pragma unroll
    for (int it = 0; it < 4; ++it) GLD16(bbase + boff[it], dst + it * 4096);
  };

  // prologue: stage step 0, then issue step-0 gathers (stage older than gathers)
  stageB(0);
  newKpt(0);
  loadC(0);
  const int laneoff = lr * 64 + ((lq ^ ((lr ^ (lr >> 2)) & 3)) << 4);

  for (int ks = 0; ks < 72; ++ks) {
    // stage NEXT step's B (stays in flight across the barrier)
    if (ks < 71) stageB(ks + 1);
    // interp current A-fragments — compiler waits counted vmcnt for gathers(ks),
    // which also drains the older stage(ks); stage(ks+1) remains outstanding.
    short8 af[2];
#pragma unroll
    for (int r = 0; r < 2; ++r) {
      u16 rr[8];
      const unsigned* u0 = (const unsigned*)&cv[r][0];
      const unsigned* u1 = (const unsigned*)&cv[r][1];
      const unsigned* u2 = (const unsigned*)&cv[r][2];
      const unsigned* u3 = (const unsigned*)&cv[r][3];
#pragma unroll
      for (int j2 = 0; j2 < 4; ++j2) {
        unsigned a0 = u0[j2], a1 = u1[j2], a2 = u2[j2], a3 = u3[j2];
        float l0, h0, l1, h1, l2, h2, l3, h3;
        unsigned tl_, th_;
        tl_ = a0 << 16; th_ = a0 & 0xFFFF0000u;
        __builtin_memcpy(&l0, &tl_, 4); __builtin_memcpy(&h0, &th_, 4);
        tl_ = a1 << 16; th_ = a1 & 0xFFFF0000u;
        __builtin_memcpy(&l1, &tl_, 4); __builtin_memcpy(&h1, &th_, 4);
        tl_ = a2 << 16; th_ = a2 & 0xFFFF0000u;
        __builtin_memcpy(&l2, &tl_, 4); __builtin_memcpy(&h2, &th_, 4);
        tl_ = a3 << 16; th_ = a3 & 0xFFFF0000u;
        __builtin_memcpy(&l3, &tl_, 4); __builtin_memcpy(&h3, &th_, 4);
        float lo = wgt[r][0] * l0 + wgt[r][1] * l1 + wgt[r][2] * l2 + wgt[r][3] * l3;
        float hi = wgt[r][0] * h0 + wgt[r][1] * h1 + wgt[r][2] * h2 + wgt[r][3] * h3;
        __hip_bfloat16 hl = __float2bfloat16(lo);
        __hip_bfloat16 hh = __float2bfloat16(hi);
        rr[2 * j2]     = *(u16*)&hl;
        rr[2 * j2 + 1] = *(u16*)&hh;
      }
      af[r] = *(short8*)rr;
    }
    if (ks < 71 && (((ks + 1) & 7) == 0)) newKpt((ks + 1) >> 3);
    // all waves' stage(ks) complete (implied by their interp waits) -> one raw barrier
    __builtin_amdgcn_s_barrier();
    __builtin_amdgcn_sched_barrier(0);
    // issue next step's corner gathers — covered by the MFMA cluster below
    if (ks < 71) loadC(ks + 1);
    const char* base = (const char*)sB[ks % 3] + laneoff;
    __builtin_amdgcn_s_setprio(1);
#pragma unroll
    for (int n = 0; n < 16; ++n) {
      short8 bfr = *(const short8*)(base + n * 1024);
      acc[0][n] = __builtin_amdgcn_mfma_f32_16x16x32_bf16(af[0], bfr, acc[0][n], 0, 0, 0);
      acc[1][n] = __builtin_amdgcn_mfma_f32_16x16x32_bf16(af[1], bfr, acc[1][n], 0, 0, 0);
    }
    __builtin_amdgcn_s_setprio(0);
  }

  // epilogue: D rows = pixel (lq*4+q), cols = oc (n*16+lr)
#pragma unroll
  for (int r = 0; r < 2; ++r) {
    int prow = p0 + w * 32 + r * 16 + lq * 4;
#pragma unroll
    for (int n = 0; n < 16; ++n) {
      int oc = n * 16 + lr;
      float sc = 1.f, sh = 0.f;
      if constexpr (EPI == 3) { sc = scale[oc]; sh = shift[oc]; }
#pragma unroll
      for (int q = 0; q < 4; ++q) {
        float v = acc[r][n][q];
        if constexpr (EPI == 3) v = fmaxf(v * sc + sh, 0.f);
        oB[(size_t)(prow + q) * 256 + oc] = f2bf(v);
      }
    }
  }
}

// ---------------- unified MFMA GEMM (dense / im2col), BK=64, XOR-swizzled LDS
// MODE 0: A dense bf16 [M][Ktot]
// MODE 1: A NHWC bf16 [(lvl,128,128)][256], im2col 3x3 pad=1 (k = kpt*256+c)
// EPI 1: fp32 [p][32] + bias(oc<18)   2: bf16 [p][256]   3: bn+relu bf16 [p][256]
// EPI 4: fp32 NCHW + bias (oc<OutN)   5: fp32 NCHW bn+relu
template<int MODE, int AM, int AN, int MW, int NW, int EPI>
__launch_bounds__(MW*NW*64)
__global__ void mm_k(const u16* __restrict__ A, const u16* __restrict__ B,
                     const u16* __restrict__ zbuf,
                     float* __restrict__ oF, u16* __restrict__ oB,
                     const float* __restrict__ bias,
                     const float* __restrict__ scale, const float* __restrict__ shift,
                     int Ktot, int ksteps, int OutN) {
  constexpr int BM = MW * AM * 16, BN = NW * AN * 16, NT = MW * NW * 64;
  constexpr int AITS = BM * 8 / NT, BITS = BN * 8 / NT;
  __shared__ u16 sA[BM * 64];
  __shared__ u16 sB[BN * 64];
  char* sAb = (char*)sA; char* sBb = (char*)sB;
  const int t = threadIdx.x;
  const int w = t >> 6, l = t & 63;
  const int lr = l & 15, lq = l >> 4;
  const int wm = w / NW, wn = w % NW;
  int bx = blockIdx.x;
  { int n8 = gridDim.x >> 3; bx = (bx & 7) * n8 + (bx >> 3); }
  const int p0 = bx * BM, n0 = blockIdx.y * BN;

  f32x4 acc[AM][AN];
#pragma unroll
  for (int m = 0; m < AM; ++m)
#pragma unroll
    for (int n = 0; n < AN; ++n) acc[m][n] = (f32x4){0.f, 0.f, 0.f, 0.f};

  for (int ks = 0; ks < ksteps; ++ks) {
    int k0 = ks * 64;
#pragma unroll
    for (int it = 0; it < BITS; ++it) {
      int ch = it * NT + t;
      int row = ch >> 3, cl = (ch & 7) ^ (row & 7);
      GLD16(B + (size_t)(n0 + row) * Ktot + k0 + cl * 8, sBb + it * (NT * 16) + w * 1024);
    }
    if constexpr (MODE == 0) {
#pragma unroll
      for (int it = 0; it < AITS; ++it) {
        int ch = it * NT + t;
        int row = ch >> 3, cl = (ch & 7) ^ (row & 7);
        GLD16(A + (size_t)(p0 + row) * Ktot + k0 + cl * 8, sAb + it * (NT * 16) + w * 1024);
      }
    } else {
      int kpt = k0 >> 8, c0 = k0 & 255;
      int dy = kpt / 3 - 1, dx = kpt % 3 - 1;
#pragma unroll
      for (int it = 0; it < AITS; ++it) {
        int ch = it * NT + t;
        int row = ch >> 3, cl = (ch & 7) ^ (row & 7);
        int gp = p0 + row; int lvl = gp >> 14, pl = gp & 16383;
        int yy = (pl >> 7) + dy, xx = (pl & 127) + dx;
        const u16* src = ((unsigned)yy < 128u && (unsigned)xx < 128u)
            ? A + ((size_t)(lvl << 14) + (yy << 7) + xx) * 256 + c0 + cl * 8
            : zbuf;
        GLD16(src, sAb + it * (NT * 16) + w * 1024);
      }
    }
    __syncthreads();
    short8 af[AM], bfr[AN];
#pragma unroll
    for (int h = 0; h < 2; ++h) {
#pragma unroll
      for (int m = 0; m < AM; ++m) {
        int ar = wm * AM * 16 + m * 16 + lr;
        af[m] = *(const short8*)(sAb + ar * 128 + (((h * 4 + lq) ^ (ar & 7)) << 4));
      }
#pragma unroll
      for (int n = 0; n < AN; ++n) {
        int br = wn * AN * 16 + n * 16 + lr;
        bfr[n] = *(const short8*)(sBb + br * 128 + (((h * 4 + lq) ^ (br & 7)) << 4));
      }
#pragma unroll
      for (int m = 0; m < AM; ++m)
#pragma unroll
        for (int n = 0; n < AN; ++n)
          acc[m][n] = __builtin_amdgcn_mfma_f32_16x16x32_bf16(af[m], bfr[n], acc[m][n], 0, 0, 0);
    }
    __syncthreads();
  }

#pragma unroll
  for (int m = 0; m < AM; ++m) {
    int prow = p0 + wm * AM * 16 + m * 16 + lq * 4;
#pragma unroll
    for (int n = 0; n < AN; ++n) {
      int oc = n0 + wn * AN * 16 + n * 16 + lr;
      if constexpr (EPI == 1) {
        float bs = (oc < 18) ? bias[oc] : 0.f;
#pragma unroll
        for (int r = 0; r < 4; ++r) oF[(size_t)(prow + r) * 32 + oc] = acc[m][n][r] + bs;
      } else if constexpr (EPI == 2) {
#pragma unroll
        for (int r = 0; r < 4; ++r) oB[(size_t)(prow + r) * 256 + oc] = f2bf(acc[m][n][r]);
      } else if constexpr (EPI == 3) {
        float sc = scale[oc], sh = shift[oc];
#pragma unroll
        for (int r = 0; r < 4; ++r)
          oB[(size_t)(prow + r) * 256 + oc] = f2bf(fmaxf(acc[m][n][r] * sc + sh, 0.f));
      } else if constexpr (EPI == 4) {
        if (oc < OutN) {
          float bs = bias[oc];
          float4 v = {acc[m][n][0] + bs, acc[m][n][1] + bs, acc[m][n][2] + bs, acc[m][n][3] + bs};
          *(float4*)(oF + (size_t)oc * PP + prow) = v;
        }
      } else {
        float sc = scale[oc], sh = shift[oc];
        float4 v = {fmaxf(acc[m][n][0] * sc + sh, 0.f), fmaxf(acc[m][n][1] * sc + sh, 0.f),
                    fmaxf(acc[m][n][2] * sc + sh, 0.f), fmaxf(acc[m][n][3] * sc + sh, 0.f)};
        *(float4*)(oF + (size_t)oc * PP + prow) = v;
      }
    }
  }
}

// ---------------- sum 5 branch outputs (bf16) in fp32 -> bf16
__global__ void sum5_k(const u16* __restrict__ H2, u16* __restrict__ out) {
  size_t base = ((size_t)blockIdx.x * 256 + threadIdx.x) * 8;
  float a[8] = {0,0,0,0,0,0,0,0};
#pragma unroll
  for (int lvl = 0; lvl < 5; ++lvl) {
    short8 v = *(const short8*)(H2 + (size_t)lvl * PP * 256 + base);
#pragma unroll
    for (int j = 0; j < 8; ++j) a[j] += bf2f((u16)v[j]);
  }
  u16 r[8];
#pragma unroll
  for (int j = 0; j < 8; ++j) r[j] = f2bf(a[j]);
  *(short8*)(out + base) = *(short8*)r;
}

extern "C" void kernel_launch(void* const* d_in, const int* in_sizes, int n_in,
                              void* d_out, int out_size, void* d_ws, size_t ws_size,
                              hipStream_t stream) {
  const float* feats[5];
  for (int i = 0; i < 5; ++i) feats[i] = (const float*)d_in[i];
  int fsz[5] = {256, 128, 64, 32, 16};
  const float* off1_w = (const float*)d_in[5];
  const float* off1_b = (const float*)d_in[6];
  const float* dc1_w  = (const float*)d_in[7];
  const float* off2_w = (const float*)d_in[8];
  const float* off2_b = (const float*)d_in[9];
  const float* dc2_w  = (const float*)d_in[10];
  const float* bn2_g  = (const float*)d_in[11];
  const float* bn2_b  = (const float*)d_in[12];
  const float* bn2_m  = (const float*)d_in[13];
  const float* bn2_v  = (const float*)d_in[14];
  const float* convs_w = (const float*)d_in[15];
  const float* convs_g = (const float*)d_in[16];
  const float* convs_b = (const float*)d_in[17];
  const float* convs_m = (const float*)d_in[18];
  const float* convs_v = (const float*)d_in[19];
  const float* emb_w  = (const float*)d_in[20];
  const float* emb_g  = (const float*)d_in[21];
  const float* emb_b  = (const float*)d_in[22];
  const float* emb_m  = (const float*)d_in[23];
  const float* emb_v  = (const float*)d_in[24];
  const float* logit_w = (const float*)d_in[25];
  const float* logit_b = (const float*)d_in[26];

  char* ws = (char*)d_ws;
  size_t off = 0;
  auto alloc = [&](size_t bytes) { char* p = ws + off; off += (bytes + 255) & ~255ull; return p; };
  float* bnscale = (float*)alloc(6 * 256 * 4);
  float* bnshift = (float*)alloc(6 * 256 * 4);
  u16* zbuf = (u16*)alloc(256);
  u16* W2_off1 = (u16*)alloc((size_t)32 * 2304 * 2);
  u16* W2_off2 = (u16*)alloc((size_t)32 * 2304 * 2);
  u16* W2_dc1  = (u16*)alloc((size_t)256 * 2304 * 2);
  u16* W2_dc2  = (u16*)alloc((size_t)256 * 2304 * 2);
  u16* W2_c    = (u16*)alloc((size_t)4 * 256 * 2304 * 2);
  u16* W2_logit = (u16*)alloc((size_t)256 * 256 * 2);
  u16* W2_emb   = (u16*)alloc((size_t)256 * 256 * 2);
  u16* R_all  = (u16*)alloc((size_t)5 * PP * 256 * 2);
  u16* H_all  = (u16*)alloc((size_t)5 * PP * 256 * 2);
  u16* H2_all = (u16*)alloc((size_t)5 * PP * 256 * 2);
  float* O    = (float*)alloc((size_t)5 * PP * 32 * 4);
  u16* Xb     = (u16*)alloc((size_t)PP * 256 * 2);
  u16* Ftmp = H_all;                      // transpose scratch (dead before dc1 output)
  u16* cb0 = R_all;                       // conv-stack ping-pong (R dead by then)
  u16* cb1 = R_all + (size_t)PP * 256;

  hipMemsetAsync(zbuf, 0, 256, stream);
  bn_prep_k<<<1, 256, 0, stream>>>(bn2_g, bn2_b, bn2_m, bn2_v, convs_g, convs_b, convs_m, convs_v,
                                   emb_g, emb_b, emb_m, emb_v, bnscale, bnshift);
  auto pw = [&](const float* src, u16* dst, int Ocnt, int KK, int NPAD) {
    int total = NPAD * KK * 256;
    prep_w_k<<<(total + 255) / 256, 256, 0, stream>>>(src, dst, Ocnt, KK, NPAD);
  };
  pw(off1_w, W2_off1, 18, 9, 32);
  pw(off2_w, W2_off2, 18, 9, 32);
  pw(dc1_w,  W2_dc1, 256, 9, 256);
  pw(dc2_w,  W2_dc2, 256, 9, 256);
  for (int i = 0; i < 4; ++i) pw(convs_w + (size_t)i * 2304 * 256, W2_c + (size_t)i * 2304 * 256, 256, 9, 256);
  pw(logit_w, W2_logit, 183, 1, 256);
  pw(emb_w,   W2_emb,   256, 1, 256);

  const dim3 blk(256);
  // ---- build R_all: NHWC bf16 at 128x128 per level
  for (int lvl = 0; lvl < 5; ++lvl) {
    int P = fsz[lvl] * fsz[lvl];
    u16* dst = (lvl == 1) ? (R_all + (size_t)PP * 256) : Ftmp;
    tr_k<<<dim3(P / 64, 4), blk, 0, stream>>>(feats[lvl], dst, P);
    if (lvl != 1)
      rs_k<<<dim3(PP / 8), blk, 0, stream>>>(Ftmp, R_all + (size_t)lvl * PP * 256, fsz[lvl]);
  }

  constexpr int MG = 5 * PP;  // 81920 rows batched
  // off1 (batched im2col conv) -> O fp32 [gp][32]
  mm_k<1, 2, 2, 4, 1, 1><<<dim3(MG / 128, 1), blk, 0, stream>>>(
      R_all, W2_off1, zbuf, O, nullptr, off1_b, nullptr, nullptr, 2304, 36, 32);
  // dc1 (fused deform, A-in-regs) -> H_all bf16
  dc_k<2><<<dim3(MG / 128), blk, 0, stream>>>(R_all, W2_dc1, O, H_all, nullptr, nullptr);
  // off2 (batched)
  mm_k<1, 2, 2, 4, 1, 1><<<dim3(MG / 128, 1), blk, 0, stream>>>(
      H_all, W2_off2, zbuf, O, nullptr, off2_b, nullptr, nullptr, 2304, 36, 32);
  // dc2 (fused deform, bn+relu) -> H2_all bf16
  dc_k<3><<<dim3(MG / 128), blk, 0, stream>>>(H_all, W2_dc2, O, H2_all, bnscale, bnshift);

  // ---- sum branches
  sum5_k<<<dim3(2048), blk, 0, stream>>>(H2_all, Xb);

  // ---- conv stack (64x128 tiles, grid 512)
  const u16* cur = Xb;
  u16* cbuf[2] = {cb0, cb1};
  for (int i = 0; i < 4; ++i) {
    mm_k<1, 2, 4, 2, 2, 3><<<dim3(PP / 64, 2), blk, 0, stream>>>(
        cur, W2_c + (size_t)i * 2304 * 256, zbuf, nullptr, cbuf[i & 1],
        nullptr, bnscale + (1 + i) * 256, bnshift + (1 + i) * 256, 2304, 36, 256);
    cur = cbuf[i & 1];
  }

  // ---- heads (1x1, K=256)
  float* outp = (float*)d_out;
  mm_k<0, 2, 4, 2, 2, 4><<<dim3(PP / 64, 2), blk, 0, stream>>>(
      cur, W2_logit, zbuf, outp, nullptr, logit_b, nullptr, nullptr, 256, 4, 183);
  mm_k<0, 2, 4, 2, 2, 5><<<dim3(PP / 64, 2), blk, 0, stream>>>(
      cur, W2_emb, zbuf, outp + (size_t)183 * PP, nullptr, nullptr,
      bnscale + 5 * 256, bnshift + 5 * 256, 256, 4, 256);
}

// Round 10
// 825.787 us; speedup vs baseline: 1.1965x; 1.1965x over previous
//
#include <hip/hip_runtime.h>
#include <hip/hip_bf16.h>
#include <stdint.h>

#define EPS_BN 1e-5f
constexpr int PP = 16384;   // 128*128 pixels at fusion resolution
using short8 = __attribute__((ext_vector_type(8))) short;
using f32x4  = __attribute__((ext_vector_type(4))) float;
typedef unsigned short u16;

__device__ inline float bf2f(u16 u) {
  unsigned v = ((unsigned)u) << 16; float f; __builtin_memcpy(&f, &v, 4); return f;
}
__device__ inline u16 f2bf(float f) {
  unsigned b; __builtin_memcpy(&b, &f, 4);
  b += 0x7FFFu + ((b >> 16) & 1u);
  return (u16)(b >> 16);
}
__device__ inline float u2f(unsigned x) { float f; __builtin_memcpy(&f, &x, 4); return f; }

#define GLD16(g, l) __builtin_amdgcn_global_load_lds( \
    (__attribute__((address_space(1))) void*)(void*)(g), \
    (__attribute__((address_space(3))) void*)(void*)(l), 16, 0, 0)

// ---------------- BN param prep ----------------
__global__ void bn_prep_k(const float* __restrict__ g0, const float* __restrict__ b0,
                          const float* __restrict__ m0, const float* __restrict__ v0,
                          const float* __restrict__ cg, const float* __restrict__ cb,
                          const float* __restrict__ cm, const float* __restrict__ cv,
                          const float* __restrict__ eg, const float* __restrict__ eb,
                          const float* __restrict__ em, const float* __restrict__ ev,
                          float* __restrict__ scale, float* __restrict__ shift) {
  int c = threadIdx.x;
  float s = g0[c] * rsqrtf(v0[c] + EPS_BN);
  scale[c] = s; shift[c] = b0[c] - m0[c] * s;
#pragma unroll
  for (int i = 0; i < 4; ++i) {
    float si = cg[i*256+c] * rsqrtf(cv[i*256+c] + EPS_BN);
    scale[(1+i)*256+c] = si; shift[(1+i)*256+c] = cb[i*256+c] - cm[i*256+c]*si;
  }
  float se = eg[c] * rsqrtf(ev[c] + EPS_BN);
  scale[5*256+c] = se; shift[5*256+c] = eb[c] - em[c]*se;
}

// ---------------- weight prep (row-major oc x K): w[O][256][KK] fp32 -> W2[o][k*256+c] bf16
__global__ void prep_w_k(const float* __restrict__ w, u16* __restrict__ W2,
                         int Ocnt, int KK, int NPAD) {
  int idx = blockIdx.x * 256 + threadIdx.x;
  int total = NPAD * KK * 256;
  if (idx >= total) return;
  int o = idx / (KK * 256); int rem = idx - o * (KK * 256);
  int kpt = rem >> 8, c = rem & 255;
  W2[idx] = (o < Ocnt) ? f2bf(w[(o * 256 + c) * KK + kpt]) : (u16)0;
}

// ---------------- weight prep (fragment-major for dc_k): w[256][256][9] fp32 ->
// W2f[ks][n][lane][j]  (u16 idx = ks*8192 + n*512 + lane*8 + j)
// element: oc = n*16 + (lane&15); k = ks*32 + (lane>>4)*8 + j; kpt = k>>8; c = k&255
__global__ void prep_wf_k(const float* __restrict__ w, u16* __restrict__ W2f) {
  int idx = blockIdx.x * 256 + threadIdx.x;   // total 72*8192 = 589824
  int ks = idx >> 13, r = idx & 8191;
  int n = r >> 9, r2 = r & 511;
  int lane = r2 >> 3, j = r2 & 7;
  int k = ks * 32 + ((lane >> 4) << 3) + j;
  int oc = n * 16 + (lane & 15);
  W2f[idx] = f2bf(w[(oc * 256 + (k & 255)) * 9 + (k >> 8)]);
}

// ---------------- NCHW fp32 -> NHWC bf16 transpose
__global__ void tr_k(const float* __restrict__ in, u16* __restrict__ out, int P) {
  __shared__ float tile[64][65];
  int p0 = blockIdx.x * 64, c0 = blockIdx.y * 64;
  int t = threadIdx.x;
  int tl = t & 63, tg = t >> 6;
#pragma unroll
  for (int i = 0; i < 16; ++i) {
    int c = tg * 16 + i;
    tile[c][tl] = in[(size_t)(c0 + c) * P + p0 + tl];
  }
  __syncthreads();
  int px = t >> 2, cq = t & 3;
#pragma unroll
  for (int pass = 0; pass < 2; ++pass) {
    int c = cq * 8 + pass * 32;
    u16 r[8];
#pragma unroll
    for (int j = 0; j < 8; ++j) r[j] = f2bf(tile[c + j][px]);
    *(short8*)(out + (size_t)(p0 + px) * 256 + c0 + c) = *(short8*)r;
  }
}

// ---------------- bilinear resize (align_corners) NHWC bf16 -> 128x128 NHWC bf16
__global__ void rs_k(const u16* __restrict__ in, u16* __restrict__ out, int Hs) {
  int t = threadIdx.x;
  int p = blockIdx.x * 8 + (t >> 5), q = t & 31;
  int oy = p >> 7, ox = p & 127;
  float sc = (float)(Hs - 1) / 127.0f;
  float ys = oy * sc, xs = ox * sc;
  int y0 = (int)ys; if (y0 > Hs - 2) y0 = Hs - 2;
  int x0 = (int)xs; if (x0 > Hs - 2) x0 = Hs - 2;
  float wy = ys - (float)y0, wx = xs - (float)x0;
  const u16* b00 = in + ((size_t)(y0 * Hs + x0)) * 256 + q * 8;
  short8 v00 = *(const short8*)b00;
  short8 v01 = *(const short8*)(b00 + 256);
  short8 v10 = *(const short8*)(b00 + (size_t)Hs * 256);
  short8 v11 = *(const short8*)(b00 + (size_t)Hs * 256 + 256);
  u16 r[8];
#pragma unroll
  for (int j = 0; j < 8; ++j) {
    float a = bf2f((u16)v00[j]) * (1.f - wx) + bf2f((u16)v01[j]) * wx;
    float b = bf2f((u16)v10[j]) * (1.f - wx) + bf2f((u16)v11[j]) * wx;
    r[j] = f2bf(a * (1.f - wy) + b * wy);
  }
  *(short8*)(out + (size_t)p * 256 + q * 8) = *(short8*)r;
}

// ---------------- deform-conv MFMA GEMM: A sampled into registers, B triple-buf LDS
// C[p,oc] = sum_k sample(A)[p,k] * Bw2[frag-major];  BM=64 (wave -> 16 rows), BN=256, BK=32
// B staged as a LINEAR 16KB copy of the fragment-major weight tile -> conflict-free
// contiguous ds_read (lane*16). One raw s_barrier/step, triple buffer, counted vmcnt.
// EPI 2: plain bf16 out [p][256]   EPI 3: bn+relu bf16 out
template<int EPI>
__launch_bounds__(256, 3)
__global__ void dc_k(const u16* __restrict__ A, const u16* __restrict__ Bw2,
                     const float* __restrict__ offs, u16* __restrict__ oB,
                     const float* __restrict__ scale, const float* __restrict__ shift) {
  __shared__ u16 sB[3][256 * 32];
  const int t = threadIdx.x, w = t >> 6, l = t & 63, lr = l & 15, lq = l >> 4;
  int bx = blockIdx.x; { int n8 = gridDim.x >> 3; bx = (bx & 7) * n8 + (bx >> 3); }
  const int p0 = bx * 64;
  const int gp = p0 + w * 16 + lr;
  const int pl = gp & 16383, lb = gp & ~16383;

  f32x4 acc[16];
#pragma unroll
  for (int n = 0; n < 16; ++n) acc[n] = (f32x4){0.f, 0.f, 0.f, 0.f};

  float wgt[4];
  int   cb[4];
  short8 cv[4];
  float2 onext;
  const short8 z8 = (short8){0, 0, 0, 0, 0, 0, 0, 0};

  onext = *(const float2*)(offs + (size_t)gp * 32);

  auto newKpt = [&](int kpt) {
    float2 o2 = onext;
    if (kpt < 8) onext = *(const float2*)(offs + (size_t)gp * 32 + 2 * (kpt + 1));
    float yy = (float)((pl >> 7) + kpt / 3 - 1) + o2.x;
    float xx = (float)((pl & 127) + kpt % 3 - 1) + o2.y;
    float yf = floorf(yy), xf = floorf(xx);
    float fy = yy - yf, fx = xx - xf;
    int y0 = (int)yf, x0 = (int)xf;
    bool va = (unsigned)y0 < 128u, vb = (unsigned)(y0 + 1) < 128u;
    bool ha = (unsigned)x0 < 128u, hb = (unsigned)(x0 + 1) < 128u;
    wgt[0] = (1.f - fy) * (1.f - fx); cb[0] = (va && ha) ? lb + (y0 << 7) + x0 : -1;
    wgt[1] = (1.f - fy) * fx;         cb[1] = (va && hb) ? lb + (y0 << 7) + x0 + 1 : -1;
    wgt[2] = fy * (1.f - fx);         cb[2] = (vb && ha) ? lb + ((y0 + 1) << 7) + x0 : -1;
    wgt[3] = fy * fx;                 cb[3] = (vb && hb) ? lb + ((y0 + 1) << 7) + x0 + 1 : -1;
  };
  auto loadC = [&](int ks) {
    int cc = ((ks & 7) << 5) + lq * 8;
#pragma unroll
    for (int c = 0; c < 4; ++c)
      cv[c] = (cb[c] >= 0) ? *(const short8*)(A + (size_t)cb[c] * 256 + cc) : z8;
  };
  auto stageB = [&](int ks) {
    const u16* src = Bw2 + (size_t)ks * 8192 + t * 8;
    char* dst = (char*)sB[ks % 3] + t * 16;
#pragma unroll
    for (int it = 0; it < 4; ++it) GLD16(src + it * 2048, dst + it * 4096);
  };

  // prologue: stage(0) older than gathers(0)
  stageB(0);
  newKpt(0);
  loadC(0);

  for (int ks = 0; ks < 72; ++ks) {
    // stage NEXT step's B (newer than gathers(ks) -> stays in flight across barrier)
    if (ks < 71) stageB(ks + 1);
    // interp current A-fragment; cv-use forces counted vmcnt (drains stage(ks)+loadC(ks))
    short8 af;
    {
      u16 rr[8];
      const unsigned* u0 = (const unsigned*)&cv[0];
      const unsigned* u1 = (const unsigned*)&cv[1];
      const unsigned* u2 = (const unsigned*)&cv[2];
      const unsigned* u3 = (const unsigned*)&cv[3];
#pragma unroll
      for (int j2 = 0; j2 < 4; ++j2) {
        unsigned a0 = u0[j2], a1 = u1[j2], a2 = u2[j2], a3 = u3[j2];
        float lo = wgt[0] * u2f(a0 << 16) + wgt[1] * u2f(a1 << 16)
                 + wgt[2] * u2f(a2 << 16) + wgt[3] * u2f(a3 << 16);
        float hi = wgt[0] * u2f(a0 & 0xFFFF0000u) + wgt[1] * u2f(a1 & 0xFFFF0000u)
                 + wgt[2] * u2f(a2 & 0xFFFF0000u) + wgt[3] * u2f(a3 & 0xFFFF0000u);
        __hip_bfloat16 hl = __float2bfloat16(lo);
        __hip_bfloat16 hh = __float2bfloat16(hi);
        rr[2 * j2]     = *(u16*)&hl;
        rr[2 * j2 + 1] = *(u16*)&hh;
      }
      af = *(short8*)rr;
    }
    if (ks < 71 && (((ks + 1) & 7) == 0)) newKpt((ks + 1) >> 3);
    // pin interp (and its vmcnt wait) before the barrier, then sync
    __builtin_amdgcn_sched_barrier(0);
    __builtin_amdgcn_s_barrier();
    __builtin_amdgcn_sched_barrier(0);
    // issue next step's corner gathers — covered by the MFMA cluster below
    if (ks < 71) loadC(ks + 1);
    const char* base = (const char*)sB[ks % 3] + l * 16;
    __builtin_amdgcn_s_setprio(1);
#pragma unroll
    for (int n = 0; n < 16; ++n) {
      short8 bfr = *(const short8*)(base + n * 1024);
      acc[n] = __builtin_amdgcn_mfma_f32_16x16x32_bf16(af, bfr, acc[n], 0, 0, 0);
    }
    __builtin_amdgcn_s_setprio(0);
  }

  // epilogue: D rows = pixel (lq*4+q), cols = oc (n*16+lr)
  {
    int prow = p0 + w * 16 + lq * 4;
#pragma unroll
    for (int n = 0; n < 16; ++n) {
      int oc = n * 16 + lr;
      float sc = 1.f, sh = 0.f;
      if constexpr (EPI == 3) { sc = scale[oc]; sh = shift[oc]; }
#pragma unroll
      for (int q = 0; q < 4; ++q) {
        float v = acc[n][q];
        if constexpr (EPI == 3) v = fmaxf(v * sc + sh, 0.f);
        oB[(size_t)(prow + q) * 256 + oc] = f2bf(v);
      }
    }
  }
}

// ---------------- unified MFMA GEMM (dense / im2col), BK=64, XOR-swizzled LDS
// MODE 0: A dense bf16 [M][Ktot]
// MODE 1: A NHWC bf16 [(lvl,128,128)][256], im2col 3x3 pad=1 (k = kpt*256+c)
// EPI 1: fp32 [p][32] + bias(oc<18)   2: bf16 [p][256]   3: bn+relu bf16 [p][256]
// EPI 4: fp32 NCHW + bias (oc<OutN)   5: fp32 NCHW bn+relu
template<int MODE, int AM, int AN, int MW, int NW, int EPI>
__launch_bounds__(MW*NW*64)
__global__ void mm_k(const u16* __restrict__ A, const u16* __restrict__ B,
                     const u16* __restrict__ zbuf,
                     float* __restrict__ oF, u16* __restrict__ oB,
                     const float* __restrict__ bias,
                     const float* __restrict__ scale, const float* __restrict__ shift,
                     int Ktot, int ksteps, int OutN) {
  constexpr int BM = MW * AM * 16, BN = NW * AN * 16, NT = MW * NW * 64;
  constexpr int AITS = BM * 8 / NT, BITS = BN * 8 / NT;
  __shared__ u16 sA[BM * 64];
  __shared__ u16 sB[BN * 64];
  char* sAb = (char*)sA; char* sBb = (char*)sB;
  const int t = threadIdx.x;
  const int w = t >> 6, l = t & 63;
  const int lr = l & 15, lq = l >> 4;
  const int wm = w / NW, wn = w % NW;
  int bx = blockIdx.x;
  { int n8 = gridDim.x >> 3; bx = (bx & 7) * n8 + (bx >> 3); }
  const int p0 = bx * BM, n0 = blockIdx.y * BN;

  f32x4 acc[AM][AN];
#pragma unroll
  for (int m = 0; m < AM; ++m)
#pragma unroll
    for (int n = 0; n < AN; ++n) acc[m][n] = (f32x4){0.f, 0.f, 0.f, 0.f};

  for (int ks = 0; ks < ksteps; ++ks) {
    int k0 = ks * 64;
#pragma unroll
    for (int it = 0; it < BITS; ++it) {
      int ch = it * NT + t;
      int row = ch >> 3, cl = (ch & 7) ^ (row & 7);
      GLD16(B + (size_t)(n0 + row) * Ktot + k0 + cl * 8, sBb + it * (NT * 16) + w * 1024);
    }
    if constexpr (MODE == 0) {
#pragma unroll
      for (int it = 0; it < AITS; ++it) {
        int ch = it * NT + t;
        int row = ch >> 3, cl = (ch & 7) ^ (row & 7);
        GLD16(A + (size_t)(p0 + row) * Ktot + k0 + cl * 8, sAb + it * (NT * 16) + w * 1024);
      }
    } else {
      int kpt = k0 >> 8, c0 = k0 & 255;
      int dy = kpt / 3 - 1, dx = kpt % 3 - 1;
#pragma unroll
      for (int it = 0; it < AITS; ++it) {
        int ch = it * NT + t;
        int row = ch >> 3, cl = (ch & 7) ^ (row & 7);
        int gp = p0 + row; int lvl = gp >> 14, pl = gp & 16383;
        int yy = (pl >> 7) + dy, xx = (pl & 127) + dx;
        const u16* src = ((unsigned)yy < 128u && (unsigned)xx < 128u)
            ? A + ((size_t)(lvl << 14) + (yy << 7) + xx) * 256 + c0 + cl * 8
            : zbuf;
        GLD16(src, sAb + it * (NT * 16) + w * 1024);
      }
    }
    __syncthreads();
    short8 af[AM], bfr[AN];
#pragma unroll
    for (int h = 0; h < 2; ++h) {
#pragma unroll
      for (int m = 0; m < AM; ++m) {
        int ar = wm * AM * 16 + m * 16 + lr;
        af[m] = *(const short8*)(sAb + ar * 128 + (((h * 4 + lq) ^ (ar & 7)) << 4));
      }
#pragma unroll
      for (int n = 0; n < AN; ++n) {
        int br = wn * AN * 16 + n * 16 + lr;
        bfr[n] = *(const short8*)(sBb + br * 128 + (((h * 4 + lq) ^ (br & 7)) << 4));
      }
#pragma unroll
      for (int m = 0; m < AM; ++m)
#pragma unroll
        for (int n = 0; n < AN; ++n)
          acc[m][n] = __builtin_amdgcn_mfma_f32_16x16x32_bf16(af[m], bfr[n], acc[m][n], 0, 0, 0);
    }
    __syncthreads();
  }

#pragma unroll
  for (int m = 0; m < AM; ++m) {
    int prow = p0 + wm * AM * 16 + m * 16 + lq * 4;
#pragma unroll
    for (int n = 0; n < AN; ++n) {
      int oc = n0 + wn * AN * 16 + n * 16 + lr;
      if constexpr (EPI == 1) {
        float bs = (oc < 18) ? bias[oc] : 0.f;
#pragma unroll
        for (int r = 0; r < 4; ++r) oF[(size_t)(prow + r) * 32 + oc] = acc[m][n][r] + bs;
      } else if constexpr (EPI == 2) {
#pragma unroll
        for (int r = 0; r < 4; ++r) oB[(size_t)(prow + r) * 256 + oc] = f2bf(acc[m][n][r]);
      } else if constexpr (EPI == 3) {
        float sc = scale[oc], sh = shift[oc];
#pragma unroll
        for (int r = 0; r < 4; ++r)
          oB[(size_t)(prow + r) * 256 + oc] = f2bf(fmaxf(acc[m][n][r] * sc + sh, 0.f));
      } else if constexpr (EPI == 4) {
        if (oc < OutN) {
          float bs = bias[oc];
          float4 v = {acc[m][n][0] + bs, acc[m][n][1] + bs, acc[m][n][2] + bs, acc[m][n][3] + bs};
          *(float4*)(oF + (size_t)oc * PP + prow) = v;
        }
      } else {
        float sc = scale[oc], sh = shift[oc];
        float4 v = {fmaxf(acc[m][n][0] * sc + sh, 0.f), fmaxf(acc[m][n][1] * sc + sh, 0.f),
                    fmaxf(acc[m][n][2] * sc + sh, 0.f), fmaxf(acc[m][n][3] * sc + sh, 0.f)};
        *(float4*)(oF + (size_t)oc * PP + prow) = v;
      }
    }
  }
}

// ---------------- sum 5 branch outputs (bf16) in fp32 -> bf16
__global__ void sum5_k(const u16* __restrict__ H2, u16* __restrict__ out) {
  size_t base = ((size_t)blockIdx.x * 256 + threadIdx.x) * 8;
  float a[8] = {0,0,0,0,0,0,0,0};
#pragma unroll
  for (int lvl = 0; lvl < 5; ++lvl) {
    short8 v = *(const short8*)(H2 + (size_t)lvl * PP * 256 + base);
#pragma unroll
    for (int j = 0; j < 8; ++j) a[j] += bf2f((u16)v[j]);
  }
  u16 r[8];
#pragma unroll
  for (int j = 0; j < 8; ++j) r[j] = f2bf(a[j]);
  *(short8*)(out + base) = *(short8*)r;
}

extern "C" void kernel_launch(void* const* d_in, const int* in_sizes, int n_in,
                              void* d_out, int out_size, void* d_ws, size_t ws_size,
                              hipStream_t stream) {
  const float* feats[5];
  for (int i = 0; i < 5; ++i) feats[i] = (const float*)d_in[i];
  int fsz[5] = {256, 128, 64, 32, 16};
  const float* off1_w = (const float*)d_in[5];
  const float* off1_b = (const float*)d_in[6];
  const float* dc1_w  = (const float*)d_in[7];
  const float* off2_w = (const float*)d_in[8];
  const float* off2_b = (const float*)d_in[9];
  const float* dc2_w  = (const float*)d_in[10];
  const float* bn2_g  = (const float*)d_in[11];
  const float* bn2_b  = (const float*)d_in[12];
  const float* bn2_m  = (const float*)d_in[13];
  const float* bn2_v  = (const float*)d_in[14];
  const float* convs_w = (const float*)d_in[15];
  const float* convs_g = (const float*)d_in[16];
  const float* convs_b = (const float*)d_in[17];
  const float* convs_m = (const float*)d_in[18];
  const float* convs_v = (const float*)d_in[19];
  const float* emb_w  = (const float*)d_in[20];
  const float* emb_g  = (const float*)d_in[21];
  const float* emb_b  = (const float*)d_in[22];
  const float* emb_m  = (const float*)d_in[23];
  const float* emb_v  = (const float*)d_in[24];
  const float* logit_w = (const float*)d_in[25];
  const float* logit_b = (const float*)d_in[26];

  char* ws = (char*)d_ws;
  size_t off = 0;
  auto alloc = [&](size_t bytes) { char* p = ws + off; off += (bytes + 255) & ~255ull; return p; };
  float* bnscale = (float*)alloc(6 * 256 * 4);
  float* bnshift = (float*)alloc(6 * 256 * 4);
  u16* zbuf = (u16*)alloc(256);
  u16* W2_off1 = (u16*)alloc((size_t)32 * 2304 * 2);
  u16* W2_off2 = (u16*)alloc((size_t)32 * 2304 * 2);
  u16* W2_dc1  = (u16*)alloc((size_t)256 * 2304 * 2);   // fragment-major
  u16* W2_dc2  = (u16*)alloc((size_t)256 * 2304 * 2);   // fragment-major
  u16* W2_c    = (u16*)alloc((size_t)4 * 256 * 2304 * 2);
  u16* W2_logit = (u16*)alloc((size_t)256 * 256 * 2);
  u16* W2_emb   = (u16*)alloc((size_t)256 * 256 * 2);
  u16* R_all  = (u16*)alloc((size_t)5 * PP * 256 * 2);
  u16* H_all  = (u16*)alloc((size_t)5 * PP * 256 * 2);
  u16* H2_all = (u16*)alloc((size_t)5 * PP * 256 * 2);
  float* O    = (float*)alloc((size_t)5 * PP * 32 * 4);
  u16* Xb     = (u16*)alloc((size_t)PP * 256 * 2);
  u16* Ftmp = H_all;                      // transpose scratch (dead before dc1 output)
  u16* cb0 = R_all;                       // conv-stack ping-pong (R dead by then)
  u16* cb1 = R_all + (size_t)PP * 256;

  hipMemsetAsync(zbuf, 0, 256, stream);
  bn_prep_k<<<1, 256, 0, stream>>>(bn2_g, bn2_b, bn2_m, bn2_v, convs_g, convs_b, convs_m, convs_v,
                                   emb_g, emb_b, emb_m, emb_v, bnscale, bnshift);
  auto pw = [&](const float* src, u16* dst, int Ocnt, int KK, int NPAD) {
    int total = NPAD * KK * 256;
    prep_w_k<<<(total + 255) / 256, 256, 0, stream>>>(src, dst, Ocnt, KK, NPAD);
  };
  pw(off1_w, W2_off1, 18, 9, 32);
  pw(off2_w, W2_off2, 18, 9, 32);
  prep_wf_k<<<2304, 256, 0, stream>>>(dc1_w, W2_dc1);
  prep_wf_k<<<2304, 256, 0, stream>>>(dc2_w, W2_dc2);
  for (int i = 0; i < 4; ++i) pw(convs_w + (size_t)i * 2304 * 256, W2_c + (size_t)i * 2304 * 256, 256, 9, 256);
  pw(logit_w, W2_logit, 183, 1, 256);
  pw(emb_w,   W2_emb,   256, 1, 256);

  const dim3 blk(256);
  // ---- build R_all: NHWC bf16 at 128x128 per level
  for (int lvl = 0; lvl < 5; ++lvl) {
    int P = fsz[lvl] * fsz[lvl];
    u16* dst = (lvl == 1) ? (R_all + (size_t)PP * 256) : Ftmp;
    tr_k<<<dim3(P / 64, 4), blk, 0, stream>>>(feats[lvl], dst, P);
    if (lvl != 1)
      rs_k<<<dim3(PP / 8), blk, 0, stream>>>(Ftmp, R_all + (size_t)lvl * PP * 256, fsz[lvl]);
  }

  constexpr int MG = 5 * PP;  // 81920 rows batched
  // off1 (batched im2col conv) -> O fp32 [gp][32]
  mm_k<1, 2, 2, 4, 1, 1><<<dim3(MG / 128, 1), blk, 0, stream>>>(
      R_all, W2_off1, zbuf, O, nullptr, off1_b, nullptr, nullptr, 2304, 36, 32);
  // dc1 (fused deform, A-in-regs) -> H_all bf16
  dc_k<2><<<dim3(MG / 64), blk, 0, stream>>>(R_all, W2_dc1, O, H_all, nullptr, nullptr);
  // off2 (batched)
  mm_k<1, 2, 2, 4, 1, 1><<<dim3(MG / 128, 1), blk, 0, stream>>>(
      H_all, W2_off2, zbuf, O, nullptr, off2_b, nullptr, nullptr, 2304, 36, 32);
  // dc2 (fused deform, bn+relu) -> H2_all bf16
  dc_k<3><<<dim3(MG / 64), blk, 0, stream>>>(H_all, W2_dc2, O, H2_all, bnscale, bnshift);

  // ---- sum branches
  sum5_k<<<dim3(2048), blk, 0, stream>>>(H2_all, Xb);

  // ---- conv stack (64x64 tiles, grid 1024)
  const u16* cur = Xb;
  u16* cbuf[2] = {cb0, cb1};
  for (int i = 0; i < 4; ++i) {
    mm_k<1, 2, 2, 2, 2, 3><<<dim3(PP / 64, 4), blk, 0, stream>>>(
        cur, W2_c + (size_t)i * 2304 * 256, zbuf, nullptr, cbuf[i & 1],
        nullptr, bnscale + (1 + i) * 256, bnshift + (1 + i) * 256, 2304, 36, 256);
    cur = cbuf[i & 1];
  }

  // ---- heads (1x1, K=256)
  float* outp = (float*)d_out;
  mm_k<0, 2, 4, 2, 2, 4><<<dim3(PP / 64, 2), blk, 0, stream>>>(
      cur, W2_logit, zbuf, outp, nullptr, logit_b, nullptr, nullptr, 256, 4, 183);
  mm_k<0, 2, 4, 2, 2, 5><<<dim3(PP / 64, 2), blk, 0, stream>>>(
      cur, W2_emb, zbuf, outp + (size_t)183 * PP, nullptr, nullptr,
      bnscale + 5 * 256, bnshift + 5 * 256, 256, 4, 256);
}

// Round 11
// 778.047 us; speedup vs baseline: 1.2699x; 1.0614x over previous
//
#include <hip/hip_runtime.h>
#include <hip/hip_bf16.h>
#include <stdint.h>

#define EPS_BN 1e-5f
constexpr int PP = 16384;   // 128*128 pixels at fusion resolution
using short8 = __attribute__((ext_vector_type(8))) short;
using f32x4  = __attribute__((ext_vector_type(4))) float;
typedef unsigned short u16;

__device__ inline float bf2f(u16 u) {
  unsigned v = ((unsigned)u) << 16; float f; __builtin_memcpy(&f, &v, 4); return f;
}
__device__ inline u16 f2bf(float f) {
  unsigned b; __builtin_memcpy(&b, &f, 4);
  b += 0x7FFFu + ((b >> 16) & 1u);
  return (u16)(b >> 16);
}
__device__ inline float u2f(unsigned x) { float f; __builtin_memcpy(&f, &x, 4); return f; }

#define GLD16(g, l) __builtin_amdgcn_global_load_lds( \
    (__attribute__((address_space(1))) void*)(void*)(g), \
    (__attribute__((address_space(3))) void*)(void*)(l), 16, 0, 0)

// ---------------- BN param prep ----------------
__global__ void bn_prep_k(const float* __restrict__ g0, const float* __restrict__ b0,
                          const float* __restrict__ m0, const float* __restrict__ v0,
                          const float* __restrict__ cg, const float* __restrict__ cb,
                          const float* __restrict__ cm, const float* __restrict__ cv,
                          const float* __restrict__ eg, const float* __restrict__ eb,
                          const float* __restrict__ em, const float* __restrict__ ev,
                          float* __restrict__ scale, float* __restrict__ shift) {
  int c = threadIdx.x;
  float s = g0[c] * rsqrtf(v0[c] + EPS_BN);
  scale[c] = s; shift[c] = b0[c] - m0[c] * s;
#pragma unroll
  for (int i = 0; i < 4; ++i) {
    float si = cg[i*256+c] * rsqrtf(cv[i*256+c] + EPS_BN);
    scale[(1+i)*256+c] = si; shift[(1+i)*256+c] = cb[i*256+c] - cm[i*256+c]*si;
  }
  float se = eg[c] * rsqrtf(ev[c] + EPS_BN);
  scale[5*256+c] = se; shift[5*256+c] = eb[c] - em[c]*se;
}

// ---------------- weight prep (row-major oc x K): w[O][256][KK] fp32 -> W2[o][k*256+c] bf16
__global__ void prep_w_k(const float* __restrict__ w, u16* __restrict__ W2,
                         int Ocnt, int KK, int NPAD) {
  int idx = blockIdx.x * 256 + threadIdx.x;
  int total = NPAD * KK * 256;
  if (idx >= total) return;
  int o = idx / (KK * 256); int rem = idx - o * (KK * 256);
  int kpt = rem >> 8, c = rem & 255;
  W2[idx] = (o < Ocnt) ? f2bf(w[(o * 256 + c) * KK + kpt]) : (u16)0;
}

// ---------------- weight prep (fragment-major for dc_k): w[256][256][9] fp32 ->
// W2f[ks][n][lane][j]  (u16 idx = ks*8192 + n*512 + lane*8 + j)
// element: oc = n*16 + (lane&15); k = ks*32 + (lane>>4)*8 + j; kpt = k>>8; c = k&255
__global__ void prep_wf_k(const float* __restrict__ w, u16* __restrict__ W2f) {
  int idx = blockIdx.x * 256 + threadIdx.x;   // total 72*8192 = 589824
  int ks = idx >> 13, r = idx & 8191;
  int n = r >> 9, r2 = r & 511;
  int lane = r2 >> 3, j = r2 & 7;
  int k = ks * 32 + ((lane >> 4) << 3) + j;
  int oc = n * 16 + (lane & 15);
  W2f[idx] = f2bf(w[(oc * 256 + (k & 255)) * 9 + (k >> 8)]);
}

// ---------------- NCHW fp32 -> NHWC bf16 transpose
__global__ void tr_k(const float* __restrict__ in, u16* __restrict__ out, int P) {
  __shared__ float tile[64][65];
  int p0 = blockIdx.x * 64, c0 = blockIdx.y * 64;
  int t = threadIdx.x;
  int tl = t & 63, tg = t >> 6;
#pragma unroll
  for (int i = 0; i < 16; ++i) {
    int c = tg * 16 + i;
    tile[c][tl] = in[(size_t)(c0 + c) * P + p0 + tl];
  }
  __syncthreads();
  int px = t >> 2, cq = t & 3;
#pragma unroll
  for (int pass = 0; pass < 2; ++pass) {
    int c = cq * 8 + pass * 32;
    u16 r[8];
#pragma unroll
    for (int j = 0; j < 8; ++j) r[j] = f2bf(tile[c + j][px]);
    *(short8*)(out + (size_t)(p0 + px) * 256 + c0 + c) = *(short8*)r;
  }
}

// ---------------- bilinear resize (align_corners) NHWC bf16 -> 128x128 NHWC bf16
__global__ void rs_k(const u16* __restrict__ in, u16* __restrict__ out, int Hs) {
  int t = threadIdx.x;
  int p = blockIdx.x * 8 + (t >> 5), q = t & 31;
  int oy = p >> 7, ox = p & 127;
  float sc = (float)(Hs - 1) / 127.0f;
  float ys = oy * sc, xs = ox * sc;
  int y0 = (int)ys; if (y0 > Hs - 2) y0 = Hs - 2;
  int x0 = (int)xs; if (x0 > Hs - 2) x0 = Hs - 2;
  float wy = ys - (float)y0, wx = xs - (float)x0;
  const u16* b00 = in + ((size_t)(y0 * Hs + x0)) * 256 + q * 8;
  short8 v00 = *(const short8*)b00;
  short8 v01 = *(const short8*)(b00 + 256);
  short8 v10 = *(const short8*)(b00 + (size_t)Hs * 256);
  short8 v11 = *(const short8*)(b00 + (size_t)Hs * 256 + 256);
  u16 r[8];
#pragma unroll
  for (int j = 0; j < 8; ++j) {
    float a = bf2f((u16)v00[j]) * (1.f - wx) + bf2f((u16)v01[j]) * wx;
    float b = bf2f((u16)v10[j]) * (1.f - wx) + bf2f((u16)v11[j]) * wx;
    r[j] = f2bf(a * (1.f - wy) + b * wy);
  }
  *(short8*)(out + (size_t)p * 256 + q * 8) = *(short8*)r;
}

// ---------------- deform-conv MFMA GEMM: A sampled into registers, B triple-buf LDS
// C[p,oc] = sum_k sample(A)[p,k] * Bw2[frag-major];  BM=64 (wave -> 16 rows), BN=256, BK=32
// Branchless sampling: corner coords clamped, validity folded into weights -> no cndmask,
// no zero-vec constant. Target: arch VGPR <= 64 so total (arch+64 AGPR) fits the 128-reg
// bucket -> 4 waves/SIMD. Linear conflict-free B staging, triple buffer, one raw barrier.
// EPI 2: plain bf16 out [p][256]   EPI 3: bn+relu bf16 out
template<int EPI>
__launch_bounds__(256, 4)
__global__ void dc_k(const u16* __restrict__ A, const u16* __restrict__ Bw2,
                     const float* __restrict__ offs, u16* __restrict__ oB,
                     const float* __restrict__ scale, const float* __restrict__ shift) {
  __shared__ u16 sB[3][256 * 32];
  const int t = threadIdx.x, w = t >> 6, l = t & 63, lr = l & 15, lq = l >> 4;
  int bx = blockIdx.x; { int n8 = gridDim.x >> 3; bx = (bx & 7) * n8 + (bx >> 3); }
  const int p0 = bx * 64;
  const int gp = p0 + w * 16 + lr;
  const int pl = gp & 16383;
  const unsigned lbo = (unsigned)(gp & ~16383) * 256u;   // level base, element offset

  f32x4 acc[16];
#pragma unroll
  for (int n = 0; n < 16; ++n) acc[n] = (f32x4){0.f, 0.f, 0.f, 0.f};

  float wgt[4];
  unsigned cbo[4];     // corner element offsets (always valid, clamped)
  short8 cv[4];

  auto newKpt = [&](int kpt) {
    float2 o2 = *(const float2*)(offs + (size_t)gp * 32 + 2 * kpt);
    float yy = (float)((pl >> 7) + kpt / 3 - 1) + o2.x;
    float xx = (float)((pl & 127) + kpt % 3 - 1) + o2.y;
    float yf = floorf(yy), xf = floorf(xx);
    float fy = yy - yf, fx = xx - xf;
    int y0 = (int)yf, x0 = (int)xf;
    float gy0 = (1.f - fy) * (((unsigned)y0 < 128u) ? 1.f : 0.f);
    float gy1 = fy * (((unsigned)(y0 + 1) < 128u) ? 1.f : 0.f);
    float gx0 = (1.f - fx) * (((unsigned)x0 < 128u) ? 1.f : 0.f);
    float gx1 = fx * (((unsigned)(x0 + 1) < 128u) ? 1.f : 0.f);
    int y0c = y0 < 0 ? 0 : (y0 > 127 ? 127 : y0);
    int y1c = y0 + 1 < 0 ? 0 : (y0 + 1 > 127 ? 127 : y0 + 1);
    int x0c = x0 < 0 ? 0 : (x0 > 127 ? 127 : x0);
    int x1c = x0 + 1 < 0 ? 0 : (x0 + 1 > 127 ? 127 : x0 + 1);
    wgt[0] = gy0 * gx0; wgt[1] = gy0 * gx1; wgt[2] = gy1 * gx0; wgt[3] = gy1 * gx1;
    cbo[0] = lbo + (unsigned)((y0c << 7) + x0c) * 256u;
    cbo[1] = lbo + (unsigned)((y0c << 7) + x1c) * 256u;
    cbo[2] = lbo + (unsigned)((y1c << 7) + x0c) * 256u;
    cbo[3] = lbo + (unsigned)((y1c << 7) + x1c) * 256u;
  };
  auto loadC = [&](int ks) {
    int cc = ((ks & 7) << 5) + lq * 8;
#pragma unroll
    for (int c = 0; c < 4; ++c)
      cv[c] = *(const short8*)(A + (size_t)cbo[c] + cc);
  };
  auto stageB = [&](int ks) {
    const u16* src = Bw2 + (size_t)ks * 8192 + t * 8;
    char* dst = (char*)sB[ks % 3] + t * 16;
#pragma unroll
    for (int it = 0; it < 4; ++it) GLD16(src + it * 2048, dst + it * 4096);
  };

  // prologue: stage(0) older than gathers(0)
  stageB(0);
  newKpt(0);
  loadC(0);

  for (int ks = 0; ks < 72; ++ks) {
    // stage NEXT step's B (newer than gathers(ks) -> stays in flight across barrier)
    if (ks < 71) stageB(ks + 1);
    // interp current A-fragment; cv-use forces counted vmcnt (drains stage(ks)+loadC(ks))
    short8 af;
    {
      u16 rr[8];
      const unsigned* u0 = (const unsigned*)&cv[0];
      const unsigned* u1 = (const unsigned*)&cv[1];
      const unsigned* u2 = (const unsigned*)&cv[2];
      const unsigned* u3 = (const unsigned*)&cv[3];
#pragma unroll
      for (int j2 = 0; j2 < 4; ++j2) {
        unsigned a0 = u0[j2], a1 = u1[j2], a2 = u2[j2], a3 = u3[j2];
        float lo = wgt[0] * u2f(a0 << 16) + wgt[1] * u2f(a1 << 16)
                 + wgt[2] * u2f(a2 << 16) + wgt[3] * u2f(a3 << 16);
        float hi = wgt[0] * u2f(a0 & 0xFFFF0000u) + wgt[1] * u2f(a1 & 0xFFFF0000u)
                 + wgt[2] * u2f(a2 & 0xFFFF0000u) + wgt[3] * u2f(a3 & 0xFFFF0000u);
        __hip_bfloat16 hl = __float2bfloat16(lo);
        __hip_bfloat16 hh = __float2bfloat16(hi);
        rr[2 * j2]     = *(u16*)&hl;
        rr[2 * j2 + 1] = *(u16*)&hh;
      }
      af = *(short8*)rr;
    }
    if (ks < 71 && (((ks + 1) & 7) == 0)) newKpt((ks + 1) >> 3);
    // pin interp (and its vmcnt wait) before the barrier, then sync
    __builtin_amdgcn_sched_barrier(0);
    __builtin_amdgcn_s_barrier();
    __builtin_amdgcn_sched_barrier(0);
    // issue next step's corner gathers — covered by the MFMA cluster below
    if (ks < 71) loadC(ks + 1);
    const char* base = (const char*)sB[ks % 3] + l * 16;
    __builtin_amdgcn_s_setprio(1);
#pragma unroll
    for (int n = 0; n < 16; ++n) {
      short8 bfr = *(const short8*)(base + n * 1024);
      acc[n] = __builtin_amdgcn_mfma_f32_16x16x32_bf16(af, bfr, acc[n], 0, 0, 0);
    }
    __builtin_amdgcn_s_setprio(0);
  }

  // epilogue: D rows = pixel (lq*4+q), cols = oc (n*16+lr)
  {
    int prow = p0 + w * 16 + lq * 4;
#pragma unroll
    for (int n = 0; n < 16; ++n) {
      int oc = n * 16 + lr;
      float sc = 1.f, sh = 0.f;
      if constexpr (EPI == 3) { sc = scale[oc]; sh = shift[oc]; }
#pragma unroll
      for (int q = 0; q < 4; ++q) {
        float v = acc[n][q];
        if constexpr (EPI == 3) v = fmaxf(v * sc + sh, 0.f);
        oB[(size_t)(prow + q) * 256 + oc] = f2bf(v);
      }
    }
  }
}

// ---------------- unified MFMA GEMM (dense / im2col), BK=64, XOR-swizzled LDS
// MODE 0: A dense bf16 [M][Ktot]
// MODE 1: A NHWC bf16 [(lvl,128,128)][256], im2col 3x3 pad=1 (k = kpt*256+c)
// EPI 1: fp32 [p][32] + bias(oc<18)   2: bf16 [p][256]   3: bn+relu bf16 [p][256]
// EPI 4: fp32 NCHW + bias (oc<OutN)   5: fp32 NCHW bn+relu
template<int MODE, int AM, int AN, int MW, int NW, int EPI>
__launch_bounds__(MW*NW*64)
__global__ void mm_k(const u16* __restrict__ A, const u16* __restrict__ B,
                     const u16* __restrict__ zbuf,
                     float* __restrict__ oF, u16* __restrict__ oB,
                     const float* __restrict__ bias,
                     const float* __restrict__ scale, const float* __restrict__ shift,
                     int Ktot, int ksteps, int OutN) {
  constexpr int BM = MW * AM * 16, BN = NW * AN * 16, NT = MW * NW * 64;
  constexpr int AITS = BM * 8 / NT, BITS = BN * 8 / NT;
  __shared__ u16 sA[BM * 64];
  __shared__ u16 sB[BN * 64];
  char* sAb = (char*)sA; char* sBb = (char*)sB;
  const int t = threadIdx.x;
  const int w = t >> 6, l = t & 63;
  const int lr = l & 15, lq = l >> 4;
  const int wm = w / NW, wn = w % NW;
  int bx = blockIdx.x;
  { int n8 = gridDim.x >> 3; bx = (bx & 7) * n8 + (bx >> 3); }
  const int p0 = bx * BM, n0 = blockIdx.y * BN;

  f32x4 acc[AM][AN];
#pragma unroll
  for (int m = 0; m < AM; ++m)
#pragma unroll
    for (int n = 0; n < AN; ++n) acc[m][n] = (f32x4){0.f, 0.f, 0.f, 0.f};

  for (int ks = 0; ks < ksteps; ++ks) {
    int k0 = ks * 64;
#pragma unroll
    for (int it = 0; it < BITS; ++it) {
      int ch = it * NT + t;
      int row = ch >> 3, cl = (ch & 7) ^ (row & 7);
      GLD16(B + (size_t)(n0 + row) * Ktot + k0 + cl * 8, sBb + it * (NT * 16) + w * 1024);
    }
    if constexpr (MODE == 0) {
#pragma unroll
      for (int it = 0; it < AITS; ++it) {
        int ch = it * NT + t;
        int row = ch >> 3, cl = (ch & 7) ^ (row & 7);
        GLD16(A + (size_t)(p0 + row) * Ktot + k0 + cl * 8, sAb + it * (NT * 16) + w * 1024);
      }
    } else {
      int kpt = k0 >> 8, c0 = k0 & 255;
      int dy = kpt / 3 - 1, dx = kpt % 3 - 1;
#pragma unroll
      for (int it = 0; it < AITS; ++it) {
        int ch = it * NT + t;
        int row = ch >> 3, cl = (ch & 7) ^ (row & 7);
        int gp = p0 + row; int lvl = gp >> 14, pl = gp & 16383;
        int yy = (pl >> 7) + dy, xx = (pl & 127) + dx;
        const u16* src = ((unsigned)yy < 128u && (unsigned)xx < 128u)
            ? A + ((size_t)(lvl << 14) + (yy << 7) + xx) * 256 + c0 + cl * 8
            : zbuf;
        GLD16(src, sAb + it * (NT * 16) + w * 1024);
      }
    }
    __syncthreads();
    short8 af[AM], bfr[AN];
#pragma unroll
    for (int h = 0; h < 2; ++h) {
#pragma unroll
      for (int m = 0; m < AM; ++m) {
        int ar = wm * AM * 16 + m * 16 + lr;
        af[m] = *(const short8*)(sAb + ar * 128 + (((h * 4 + lq) ^ (ar & 7)) << 4));
      }
#pragma unroll
      for (int n = 0; n < AN; ++n) {
        int br = wn * AN * 16 + n * 16 + lr;
        bfr[n] = *(const short8*)(sBb + br * 128 + (((h * 4 + lq) ^ (br & 7)) << 4));
      }
#pragma unroll
      for (int m = 0; m < AM; ++m)
#pragma unroll
        for (int n = 0; n < AN; ++n)
          acc[m][n] = __builtin_amdgcn_mfma_f32_16x16x32_bf16(af[m], bfr[n], acc[m][n], 0, 0, 0);
    }
    __syncthreads();
  }

#pragma unroll
  for (int m = 0; m < AM; ++m) {
    int prow = p0 + wm * AM * 16 + m * 16 + lq * 4;
#pragma unroll
    for (int n = 0; n < AN; ++n) {
      int oc = n0 + wn * AN * 16 + n * 16 + lr;
      if constexpr (EPI == 1) {
        float bs = (oc < 18) ? bias[oc] : 0.f;
#pragma unroll
        for (int r = 0; r < 4; ++r) oF[(size_t)(prow + r) * 32 + oc] = acc[m][n][r] + bs;
      } else if constexpr (EPI == 2) {
#pragma unroll
        for (int r = 0; r < 4; ++r) oB[(size_t)(prow + r) * 256 + oc] = f2bf(acc[m][n][r]);
      } else if constexpr (EPI == 3) {
        float sc = scale[oc], sh = shift[oc];
#pragma unroll
        for (int r = 0; r < 4; ++r)
          oB[(size_t)(prow + r) * 256 + oc] = f2bf(fmaxf(acc[m][n][r] * sc + sh, 0.f));
      } else if constexpr (EPI == 4) {
        if (oc < OutN) {
          float bs = bias[oc];
          float4 v = {acc[m][n][0] + bs, acc[m][n][1] + bs, acc[m][n][2] + bs, acc[m][n][3] + bs};
          *(float4*)(oF + (size_t)oc * PP + prow) = v;
        }
      } else {
        float sc = scale[oc], sh = shift[oc];
        float4 v = {fmaxf(acc[m][n][0] * sc + sh, 0.f), fmaxf(acc[m][n][1] * sc + sh, 0.f),
                    fmaxf(acc[m][n][2] * sc + sh, 0.f), fmaxf(acc[m][n][3] * sc + sh, 0.f)};
        *(float4*)(oF + (size_t)oc * PP + prow) = v;
      }
    }
  }
}

// ---------------- sum 5 branch outputs (bf16) in fp32 -> bf16
__global__ void sum5_k(const u16* __restrict__ H2, u16* __restrict__ out) {
  size_t base = ((size_t)blockIdx.x * 256 + threadIdx.x) * 8;
  float a[8] = {0,0,0,0,0,0,0,0};
#pragma unroll
  for (int lvl = 0; lvl < 5; ++lvl) {
    short8 v = *(const short8*)(H2 + (size_t)lvl * PP * 256 + base);
#pragma unroll
    for (int j = 0; j < 8; ++j) a[j] += bf2f((u16)v[j]);
  }
  u16 r[8];
#pragma unroll
  for (int j = 0; j < 8; ++j) r[j] = f2bf(a[j]);
  *(short8*)(out + base) = *(short8*)r;
}

extern "C" void kernel_launch(void* const* d_in, const int* in_sizes, int n_in,
                              void* d_out, int out_size, void* d_ws, size_t ws_size,
                              hipStream_t stream) {
  const float* feats[5];
  for (int i = 0; i < 5; ++i) feats[i] = (const float*)d_in[i];
  int fsz[5] = {256, 128, 64, 32, 16};
  const float* off1_w = (const float*)d_in[5];
  const float* off1_b = (const float*)d_in[6];
  const float* dc1_w  = (const float*)d_in[7];
  const float* off2_w = (const float*)d_in[8];
  const float* off2_b = (const float*)d_in[9];
  const float* dc2_w  = (const float*)d_in[10];
  const float* bn2_g  = (const float*)d_in[11];
  const float* bn2_b  = (const float*)d_in[12];
  const float* bn2_m  = (const float*)d_in[13];
  const float* bn2_v  = (const float*)d_in[14];
  const float* convs_w = (const float*)d_in[15];
  const float* convs_g = (const float*)d_in[16];
  const float* convs_b = (const float*)d_in[17];
  const float* convs_m = (const float*)d_in[18];
  const float* convs_v = (const float*)d_in[19];
  const float* emb_w  = (const float*)d_in[20];
  const float* emb_g  = (const float*)d_in[21];
  const float* emb_b  = (const float*)d_in[22];
  const float* emb_m  = (const float*)d_in[23];
  const float* emb_v  = (const float*)d_in[24];
  const float* logit_w = (const float*)d_in[25];
  const float* logit_b = (const float*)d_in[26];

  char* ws = (char*)d_ws;
  size_t off = 0;
  auto alloc = [&](size_t bytes) { char* p = ws + off; off += (bytes + 255) & ~255ull; return p; };
  float* bnscale = (float*)alloc(6 * 256 * 4);
  float* bnshift = (float*)alloc(6 * 256 * 4);
  u16* zbuf = (u16*)alloc(256);
  u16* W2_off1 = (u16*)alloc((size_t)32 * 2304 * 2);
  u16* W2_off2 = (u16*)alloc((size_t)32 * 2304 * 2);
  u16* W2_dc1  = (u16*)alloc((size_t)256 * 2304 * 2);   // fragment-major
  u16* W2_dc2  = (u16*)alloc((size_t)256 * 2304 * 2);   // fragment-major
  u16* W2_c    = (u16*)alloc((size_t)4 * 256 * 2304 * 2);
  u16* W2_logit = (u16*)alloc((size_t)256 * 256 * 2);
  u16* W2_emb   = (u16*)alloc((size_t)256 * 256 * 2);
  u16* R_all  = (u16*)alloc((size_t)5 * PP * 256 * 2);
  u16* H_all  = (u16*)alloc((size_t)5 * PP * 256 * 2);
  u16* H2_all = (u16*)alloc((size_t)5 * PP * 256 * 2);
  float* O    = (float*)alloc((size_t)5 * PP * 32 * 4);
  u16* Xb     = (u16*)alloc((size_t)PP * 256 * 2);
  u16* Ftmp = H_all;                      // transpose scratch (dead before dc1 output)
  u16* cb0 = R_all;                       // conv-stack ping-pong (R dead by then)
  u16* cb1 = R_all + (size_t)PP * 256;

  hipMemsetAsync(zbuf, 0, 256, stream);
  bn_prep_k<<<1, 256, 0, stream>>>(bn2_g, bn2_b, bn2_m, bn2_v, convs_g, convs_b, convs_m, convs_v,
                                   emb_g, emb_b, emb_m, emb_v, bnscale, bnshift);
  auto pw = [&](const float* src, u16* dst, int Ocnt, int KK, int NPAD) {
    int total = NPAD * KK * 256;
    prep_w_k<<<(total + 255) / 256, 256, 0, stream>>>(src, dst, Ocnt, KK, NPAD);
  };
  pw(off1_w, W2_off1, 18, 9, 32);
  pw(off2_w, W2_off2, 18, 9, 32);
  prep_wf_k<<<2304, 256, 0, stream>>>(dc1_w, W2_dc1);
  prep_wf_k<<<2304, 256, 0, stream>>>(dc2_w, W2_dc2);
  for (int i = 0; i < 4; ++i) pw(convs_w + (size_t)i * 2304 * 256, W2_c + (size_t)i * 2304 * 256, 256, 9, 256);
  pw(logit_w, W2_logit, 183, 1, 256);
  pw(emb_w,   W2_emb,   256, 1, 256);

  const dim3 blk(256);
  // ---- build R_all: NHWC bf16 at 128x128 per level
  for (int lvl = 0; lvl < 5; ++lvl) {
    int P = fsz[lvl] * fsz[lvl];
    u16* dst = (lvl == 1) ? (R_all + (size_t)PP * 256) : Ftmp;
    tr_k<<<dim3(P / 64, 4), blk, 0, stream>>>(feats[lvl], dst, P);
    if (lvl != 1)
      rs_k<<<dim3(PP / 8), blk, 0, stream>>>(Ftmp, R_all + (size_t)lvl * PP * 256, fsz[lvl]);
  }

  constexpr int MG = 5 * PP;  // 81920 rows batched
  // off1 (batched im2col conv) -> O fp32 [gp][32]
  mm_k<1, 2, 2, 4, 1, 1><<<dim3(MG / 128, 1), blk, 0, stream>>>(
      R_all, W2_off1, zbuf, O, nullptr, off1_b, nullptr, nullptr, 2304, 36, 32);
  // dc1 (fused deform, A-in-regs) -> H_all bf16
  dc_k<2><<<dim3(MG / 64), blk, 0, stream>>>(R_all, W2_dc1, O, H_all, nullptr, nullptr);
  // off2 (batched)
  mm_k<1, 2, 2, 4, 1, 1><<<dim3(MG / 128, 1), blk, 0, stream>>>(
      H_all, W2_off2, zbuf, O, nullptr, off2_b, nullptr, nullptr, 2304, 36, 32);
  // dc2 (fused deform, bn+relu) -> H2_all bf16
  dc_k<3><<<dim3(MG / 64), blk, 0, stream>>>(H_all, W2_dc2, O, H2_all, bnscale, bnshift);

  // ---- sum branches
  sum5_k<<<dim3(2048), blk, 0, stream>>>(H2_all, Xb);

  // ---- conv stack (64x64 tiles, grid 1024)
  const u16* cur = Xb;
  u16* cbuf[2] = {cb0, cb1};
  for (int i = 0; i < 4; ++i) {
    mm_k<1, 2, 2, 2, 2, 3><<<dim3(PP / 64, 4), blk, 0, stream>>>(
        cur, W2_c + (size_t)i * 2304 * 256, zbuf, nullptr, cbuf[i & 1],
        nullptr, bnscale + (1 + i) * 256, bnshift + (1 + i) * 256, 2304, 36, 256);
    cur = cbuf[i & 1];
  }

  // ---- heads (1x1, K=256)
  float* outp = (float*)d_out;
  mm_k<0, 2, 4, 2, 2, 4><<<dim3(PP / 64, 2), blk, 0, stream>>>(
      cur, W2_logit, zbuf, outp, nullptr, logit_b, nullptr, nullptr, 256, 4, 183);
  mm_k<0, 2, 4, 2, 2, 5><<<dim3(PP / 64, 2), blk, 0, stream>>>(
      cur, W2_emb, zbuf, outp + (size_t)183 * PP, nullptr, nullptr,
      bnscale + 5 * 256, bnshift + 5 * 256, 256, 4, 256);
}